// Round 13
// baseline (43.084 us; speedup 1.0000x reference)
//
#include <hip/hip_runtime.h>
#include <hip/hip_fp16.h>

// GeneSymbolCNN: embed(67x32, pad0) -> conv1d k=2/3/4 (32ch) + ReLU + max_t
//                -> concat(96) -> 96x96 linear + ReLU.
// R13: block-parity HYBRID. Even blocks run the R12 conv-GEMM path
// (248 conv MFMAs over shared emb fragments -> matrix pipe); odd blocks
// run the R8 table-lookup path (124 ds_read_b128 -> LDS pipe). With
// 53.6KB LDS -> 2 blocks/CU, a CU's two resident blocks are adjacent
// dispatch indices -> typically one of each parity, so the LDS pipe and
// the MFMA pipe fill CONCURRENTLY (m114: heterogeneous waves co-schedule
// at ~max, not sum). Per-CU: lookup ~14us (half rows) || GEMM ~8.5us
// (half rows, corrected per-CU MFMA cost ~4.85cyc) -> ideal ~20-25us vs
// 37-39us for either pure structure.
// Each block owns rows blockIdx*128..+127 either way; both path bodies
// are verbatim their verified ancestors (R8 / R12, same absmax 4.9e-4).

#define VOCABSZ 67
#define EMBSZ   32
#define NCH     32
#define NFEAT   96
#define SEQL    16
#define BATCH   131072
#define NTAB    9
#define NFP     (NFEAT / 2)
// ---- ws layout (u32 words) ----
#define TABU    9648                   // R8 tables: 603 entries * 16 words
#define PWOFF   9648                   // packed pw: 4608 words
#define NPW     4608
#define EMB_W   14256                  // f16 emb: 1072 words
#define BFR_W   15328                  // conv B-frags: 18 * 256 words
#define NBF     18
#define WSW     19936                  // ~80 KB
// ---- LDS: path B (lookup) ----
#define ESTR    80                     // 64B entry + 16B pad
#define LTS     (VOCABSZ * ESTR)       // 5360 B per table
// ---- LDS: path A (conv-GEMM) ----
#define EMBLDS  (VOCABSZ * 128)        // 8576: 2-parity replicated emb
#define BFLDS   (NBF * 1024)           // 18432
#define FBOFF   (EMBLDS + BFLDS)       // 27008
#define FSTR    208                    // feat row stride (2-way max)
#define FBUF    (16 * FSTR)            // 3328 per wave
#define LDSB    53632                  // max(A: 53632, B: 48240)

typedef _Float16 v2h __attribute__((ext_vector_type(2)));
typedef _Float16 v8h __attribute__((ext_vector_type(8)));
typedef float    v4f __attribute__((ext_vector_type(4)));

__device__ __forceinline__ unsigned packh2(float a, float b) {
    v2h p; p[0] = (_Float16)a; p[1] = (_Float16)b;
    return __builtin_bit_cast(unsigned, p);
}

// ------------- kernel 1: tables + pw + emb + conv B-frags ------------------
__global__ __launch_bounds__(256) void build_ws(
    const float* __restrict__ embed,
    const float* __restrict__ w2, const float* __restrict__ b2,
    const float* __restrict__ w3, const float* __restrict__ b3,
    const float* __restrict__ w4, const float* __restrict__ b4,
    const float* __restrict__ pw,
    unsigned* __restrict__ ws)
{
    int idx = blockIdx.x * 256 + threadIdx.x;
    if (idx < TABU) {                      // R8 per-token tap tables
        int cp = idx & 15;
        int t  = idx >> 4;
        int j  = t / VOCABSZ;
        int v  = t - j * VOCABSZ;
        const float* w; const float* bias; int k, h;
        if (j < 2)      { w = w2; k = 2; h = j;     bias = (h == 0) ? b2 : nullptr; }
        else if (j < 5) { w = w3; k = 3; h = j - 2; bias = (h == 0) ? b3 : nullptr; }
        else            { w = w4; k = 4; h = j - 5; bias = (h == 0) ? b4 : nullptr; }
        int c0 = 2 * cp;
        float a0 = bias ? bias[c0]     : 0.0f;
        float a1 = bias ? bias[c0 + 1] : 0.0f;
        if (v != 0) {
            #pragma unroll
            for (int e = 0; e < EMBSZ; ++e) {
                float ev = embed[v * EMBSZ + e];
                a0 += ev * w[((c0    ) * EMBSZ + e) * k + h];
                a1 += ev * w[((c0 + 1) * EMBSZ + e) * k + h];
            }
        }
        ws[t * 16 + cp] = packh2(a0, a1);
    } else if (idx < EMB_W) {              // packed pw: pwh[o][fp]
        int i  = idx - PWOFF;
        int o  = i / NFP;
        int fp = i - o * NFP;
        ws[idx] = packh2(pw[o * NFEAT + 2 * fp], pw[o * NFEAT + 2 * fp + 1]);
    } else if (idx < BFR_W) {              // f16 emb, row 0 zeroed
        int i = idx - EMB_W;
        int v = i >> 4, wd = i & 15;
        int e0 = 2 * wd;
        ws[idx] = (v == 0) ? 0u
                : packh2(embed[v * EMBSZ + e0], embed[v * EMBSZ + e0 + 1]);
    } else if (idx < WSW) {                // conv B-frags (MFMA layout)
        int i    = idx - BFR_W;
        int fi   = i >> 8;
        int l    = (i >> 2) & 63;
        int wd   = i & 3;
        const float* w; int k, t, nt;
        if (fi < 4)       { w = w2; k = 2; t = fi >> 1;        nt = fi & 1; }
        else if (fi < 10) { w = w3; k = 3; t = (fi - 4) >> 1;  nt = (fi - 4) & 1; }
        else              { w = w4; k = 4; t = (fi - 10) >> 1; nt = (fi - 10) & 1; }
        int ch = 16 * nt + (l & 15);
        int e0 = 8 * (l >> 4) + 2 * wd;
        ws[idx] = packh2(w[(ch * EMBSZ + e0    ) * k + t],
                         w[(ch * EMBSZ + e0 + 1) * k + t]);
    }
}

// ------------- path A helper: conv GEMM (verbatim R12) ---------------------
template<int KT, int NP, int FI0, int CJ>
__device__ __forceinline__ void convmm(const v8h (&frag)[16],
                                       const char* __restrict__ lds,
                                       const float* __restrict__ bj,
                                       char* fb, int lane)
{
    const int nl = lane & 15, g = lane >> 4;
    #pragma unroll
    for (int nt = 0; nt < 2; ++nt) {
        float bv = bj[16 * nt + nl];
        v8h B[KT];
        #pragma unroll
        for (int t = 0; t < KT; ++t)
            B[t] = *reinterpret_cast<const v8h*>(
                lds + EMBLDS + (FI0 + 2 * t + nt) * 1024 + lane * 16);
        v4f mx = {0.f, 0.f, 0.f, 0.f};
        #pragma unroll
        for (int p = 0; p < NP; ++p) {
            v4f acc = {bv, bv, bv, bv};
            #pragma unroll
            for (int t = 0; t < KT; ++t)
                acc = __builtin_amdgcn_mfma_f32_16x16x32_f16(
                    frag[p + t], B[t], acc, 0, 0, 0);
            mx = __builtin_elementwise_max(mx, acc);
        }
        #pragma unroll
        for (int r = 0; r < 4; ++r)
            *reinterpret_cast<_Float16*>(
                fb + (4 * g + r) * FSTR + (CJ * 32 + 16 * nt + nl) * 2) =
                (_Float16)mx[r];
    }
}

// ------------- path B helper: table-lookup conv (verbatim R8) --------------
template<int K, int N, int P0, int TB>
__device__ __forceinline__ void lconv(const char* __restrict__ base,
                                      const int (&ap)[16], v8h& m)
{
    v8h s[N];
    #pragma unroll
    for (int u = 0; u < N; ++u)
        s[u] = *reinterpret_cast<const v8h*>(base + TB + ap[P0 + u]);
    #pragma unroll
    for (int h = 1; h < K; ++h) {
        v8h t[N];
        #pragma unroll
        for (int u = 0; u < N; ++u)
            t[u] = *reinterpret_cast<const v8h*>(base + TB + h * LTS + ap[P0 + u + h]);
        #pragma unroll
        for (int u = 0; u < N; ++u) s[u] = s[u] + t[u];
    }
    #pragma unroll
    for (int u = 0; u < N; ++u) m = __builtin_elementwise_max(m, s[u]);
}

// ------------- kernel 2: hybrid fused --------------------------------------
__global__ __launch_bounds__(512, 4) void fused_cnn(
    const int*      __restrict__ x,
    const unsigned* __restrict__ ws,
    const float*    __restrict__ b2,
    const float*    __restrict__ b3,
    const float*    __restrict__ b4,
    const float*    __restrict__ pb,
    float*          __restrict__ out)
{
    extern __shared__ __align__(16) char lds[];
    const int tid  = threadIdx.x;
    const int lane = tid & 63;
    const int wv   = tid >> 6;
    const int ml   = lane & 15;
    const int c    = lane >> 4;
    const int rowb = blockIdx.x * 128 + wv * 16;
    const int row  = rowb + ml;
    const bool pathA = (blockIdx.x & 1) == 0;

    // prefetch this lane's row tokens (hide HBM under staging)
    const int4* xp = reinterpret_cast<const int4*>(x + row * SEQL);
    int4 q0 = xp[0], q1 = xp[1], q2 = xp[2], q3 = xp[3];

    if (pathA) {   // stage emb (replicated) + B-frags
        const float4* s4 = reinterpret_cast<const float4*>(ws + EMB_W);
        float4* d4 = reinterpret_cast<float4*>(lds);
        if (tid < 268) {
            int v = tid >> 2, cw = tid & 3;
            float4 e = s4[tid];
            d4[v * 8 + cw]     = e;
            d4[v * 8 + 4 + cw] = e;
        }
        const float4* sb = reinterpret_cast<const float4*>(ws + BFR_W);
        float4* db = reinterpret_cast<float4*>(lds + EMBLDS);
        db[tid]       = sb[tid];
        db[tid + 512] = sb[tid + 512];
        if (tid < 128) db[tid + 1024] = sb[tid + 1024];
    } else {       // stage 9 tap-tables at 80B stride
        const float4* s4 = reinterpret_cast<const float4*>(ws);
        float4* d4 = reinterpret_cast<float4*>(lds);
        #pragma unroll
        for (int i0 = 0; i0 < 2560; i0 += 512) {
            int i = i0 + tid;
            if (i < 2412) {
                int t = i >> 2, cc = i & 3;
                d4[5 * t + cc] = s4[i];
            }
        }
    }
    __syncthreads();

    v8h m2, m3, m4;
    if (pathA) {
        const int parc = (((lane >> 3) & 1) << 6) + (c << 4);
        char* fb = lds + FBOFF + wv * FBUF;
        int tq[16];
        tq[ 0] = q0.x; tq[ 1] = q0.y; tq[ 2] = q0.z; tq[ 3] = q0.w;
        tq[ 4] = q1.x; tq[ 5] = q1.y; tq[ 6] = q1.z; tq[ 7] = q1.w;
        tq[ 8] = q2.x; tq[ 9] = q2.y; tq[10] = q2.z; tq[11] = q2.w;
        tq[12] = q3.x; tq[13] = q3.y; tq[14] = q3.z; tq[15] = q3.w;
        v8h frag[16];
        #pragma unroll
        for (int q = 0; q < 16; ++q)
            frag[q] = *reinterpret_cast<const v8h*>(lds + (tq[q] << 7) + parc);
        convmm<2, 15,  0, 0>(frag, lds, b2, fb, lane);
        convmm<3, 14,  4, 1>(frag, lds, b3, fb, lane);
        convmm<4, 13, 10, 2>(frag, lds, b4, fb, lane);
        m2 = *reinterpret_cast<const v8h*>(fb + ml * FSTR +       (c << 4));
        m3 = *reinterpret_cast<const v8h*>(fb + ml * FSTR +  64 + (c << 4));
        m4 = *reinterpret_cast<const v8h*>(fb + ml * FSTR + 128 + (c << 4));
    } else {
        const int co = c << 4;
        int ap[16];
        ap[ 0] = q0.x * ESTR + co; ap[ 1] = q0.y * ESTR + co;
        ap[ 2] = q0.z * ESTR + co; ap[ 3] = q0.w * ESTR + co;
        ap[ 4] = q1.x * ESTR + co; ap[ 5] = q1.y * ESTR + co;
        ap[ 6] = q1.z * ESTR + co; ap[ 7] = q1.w * ESTR + co;
        ap[ 8] = q2.x * ESTR + co; ap[ 9] = q2.y * ESTR + co;
        ap[10] = q2.z * ESTR + co; ap[11] = q2.w * ESTR + co;
        ap[12] = q3.x * ESTR + co; ap[13] = q3.y * ESTR + co;
        ap[14] = q3.z * ESTR + co; ap[15] = q3.w * ESTR + co;
        v8h a2 = {}, a3 = {}, a4 = {};
        lconv<2, 5,  0, 0 * LTS>(lds, ap, a2);
        lconv<2, 5,  5, 0 * LTS>(lds, ap, a2);
        lconv<2, 5, 10, 0 * LTS>(lds, ap, a2);
        lconv<3, 5,  0, 2 * LTS>(lds, ap, a3);
        lconv<3, 5,  5, 2 * LTS>(lds, ap, a3);
        lconv<3, 4, 10, 2 * LTS>(lds, ap, a3);
        lconv<4, 5,  0, 5 * LTS>(lds, ap, a4);
        lconv<4, 4,  5, 5 * LTS>(lds, ap, a4);
        lconv<4, 4,  9, 5 * LTS>(lds, ap, a4);
        m2 = a2; m3 = a3; m4 = a4;
    }

    // ---- shared projection: O[16 rows][96] via 18 MFMAs (R6-verified) ----
    const unsigned* __restrict__ pwp = ws + PWOFF + ml * NFP + c * 4;
    #pragma unroll
    for (int u = 0; u < 6; ++u) {
        v4f acc = {0.f, 0.f, 0.f, 0.f};
        v8h w0 = *reinterpret_cast<const v8h*>(pwp + 768 * u);
        v8h w1 = *reinterpret_cast<const v8h*>(pwp + 768 * u + 16);
        v8h w2 = *reinterpret_cast<const v8h*>(pwp + 768 * u + 32);
        acc = __builtin_amdgcn_mfma_f32_16x16x32_f16(m2, w0, acc, 0, 0, 0);
        acc = __builtin_amdgcn_mfma_f32_16x16x32_f16(m3, w1, acc, 0, 0, 0);
        acc = __builtin_amdgcn_mfma_f32_16x16x32_f16(m4, w2, acc, 0, 0, 0);
        float pbl = pb[16 * u + ml];
        #pragma unroll
        for (int r = 0; r < 4; ++r)
            out[(size_t)(rowb + c * 4 + r) * NFEAT + 16 * u + ml] =
                fmaxf(acc[r] + pbl, 0.f);
    }
}

extern "C" void kernel_launch(void* const* d_in, const int* in_sizes, int n_in,
                              void* d_out, int out_size, void* d_ws, size_t ws_size,
                              hipStream_t stream)
{
    const int*   x     = (const int*)  d_in[0];
    const float* embed = (const float*)d_in[1];
    const float* w2    = (const float*)d_in[2];
    const float* b2    = (const float*)d_in[3];
    const float* w3    = (const float*)d_in[4];
    const float* b3    = (const float*)d_in[5];
    const float* w4    = (const float*)d_in[6];
    const float* b4    = (const float*)d_in[7];
    const float* pw    = (const float*)d_in[8];
    const float* pb    = (const float*)d_in[9];
    float* out = (float*)d_out;
    unsigned* ws = (unsigned*)d_ws;            // ~80 KB used

    build_ws<<<(WSW + 255) / 256, 256, 0, stream>>>(
        embed, w2, b2, w3, b3, w4, b4, pw, ws);

    (void)hipFuncSetAttribute((const void*)fused_cnn,
                              hipFuncAttributeMaxDynamicSharedMemorySize,
                              LDSB);
    // grid 1024; even blocks = conv-GEMM (MFMA pipe), odd = lookup (LDS
    // pipe); 53.6KB LDS -> 2 blocks/CU -> one of each parity typically
    // resident -> pipes fill concurrently. VGPR cap 128 (512,4).
    fused_cnn<<<BATCH / 128, 512, LDSB, stream>>>(x, ws, b2, b3, b4, pb, out);
}